// Round 5
// baseline (412.382 us; speedup 1.0000x reference)
//
#include <hip/hip_runtime.h>
#include <math.h>
#include <stdint.h>

typedef unsigned int u32;
typedef unsigned long long u64;

#define BLOCK 256
#define ITEMS 16
#define CHUNK (BLOCK * ITEMS)  // 4096 elements per block

// ---------------------------------------------------------------------------
// Pass 1: per-block class histograms + 2-bit packed labels in sort's exact
// access pattern (one u32 per (block, tid)). Zero-inits loss acc + done flag.
// ---------------------------------------------------------------------------
__global__ void __launch_bounds__(BLOCK)
hist_kernel(const int* __restrict__ labels, int N,
            u32* __restrict__ hist, u32* __restrict__ plab,
            double* __restrict__ acc, u32* __restrict__ done) {
    __shared__ u32 s_cnt[4][4];  // [wave][class]
    int tid = threadIdx.x;
    int lane = tid & 63;
    int wave = tid >> 6;
    int base = blockIdx.x * CHUNK;
    u32 packed = 0;
    u32 c0 = 0, c1 = 0, c2 = 0, c3 = 0;
#pragma unroll
    for (int j = 0; j < ITEMS; ++j) {
        int idx = base + j * BLOCK + tid;
        bool valid = idx < N;
        int l = valid ? labels[idx] : 0;
        packed |= (u32)l << (2 * j);
        c0 += (valid && l == 0);
        c1 += (valid && l == 1);
        c2 += (valid && l == 2);
        c3 += (valid && l == 3);
    }
    plab[blockIdx.x * BLOCK + tid] = packed;
#pragma unroll
    for (int off = 32; off > 0; off >>= 1) {
        c0 += (u32)__shfl_down((int)c0, off, 64);
        c1 += (u32)__shfl_down((int)c1, off, 64);
        c2 += (u32)__shfl_down((int)c2, off, 64);
        c3 += (u32)__shfl_down((int)c3, off, 64);
    }
    if (lane == 0) {
        s_cnt[wave][0] = c0; s_cnt[wave][1] = c1;
        s_cnt[wave][2] = c2; s_cnt[wave][3] = c3;
    }
    __syncthreads();
    if (tid < 4)
        hist[blockIdx.x * 4 + tid] =
            s_cnt[0][tid] + s_cnt[1][tid] + s_cnt[2][tid] + s_cnt[3][tid];
    if (blockIdx.x == 0 && tid == 0) { *acc = 0.0; *done = 0u; }
}

// ---------------------------------------------------------------------------
// Pass 2: packed-label load + per-block hist prefix (L2-hot, self-waiting,
// issued before the streaming loads) + 16 float4 loads whose liveness is
// FORCED via an asm pin placed after the rank phase (the compiler's 64-VGPR
// occupancy heuristic otherwise sinks the loads into the consume loop —
// observed as VGPR_Count=64 in rounds 2-4) + ballot ranks + scatter + fused
// analytic label write + loss; last block finalizes loss (no 3rd dispatch).
// ---------------------------------------------------------------------------
struct SortShared {
    u32 s_pre[ITEMS][4][4];  // [iter][wave][class] -> excl prefix
    u32 s_red[4][8];         // [wave][bef.xyzw, tot.xyzw]
    u32 s_bc[8];             // sb0..sb3, cb1..cb3
    double s_w[4];
};

template <bool FULL>
__device__ __forceinline__ void
sort_body(SortShared& sh, const float4* __restrict__ data,
          const u32* __restrict__ plab, int N, int nb,
          const u32* __restrict__ hist, float4* __restrict__ out_data,
          float* __restrict__ out_label, double* __restrict__ acc,
          u32* __restrict__ done, float* __restrict__ out_loss) {
    int tid = threadIdx.x;
    int lane = tid & 63;
    int wave = tid >> 6;
    int base = blockIdx.x * CHUNK;

    // --- One dword: all 16 labels for this thread.
    u32 packed = plab[blockIdx.x * BLOCK + tid];
    u32 vmask;
    if (FULL) {
        vmask = 0xFFFFu;
    } else {
        int rem = N - base - tid;
        vmask = 0;
#pragma unroll
        for (int j = 0; j < ITEMS; ++j)
            vmask |= (u32)(j * BLOCK < rem) << j;
    }

    // --- Per-block hist prefix + totals (uint4, L2-hot). Self-waiting loop:
    //     runs BEFORE the 16 streaming loads (vmcnt retires in-order).
    uint4 bef = make_uint4(0, 0, 0, 0), tot = make_uint4(0, 0, 0, 0);
    {
        const uint4* h4 = (const uint4*)hist;
        u32 myb = blockIdx.x;
        for (int bb = tid; bb < nb; bb += BLOCK) {
            uint4 h = h4[bb];
            tot.x += h.x; tot.y += h.y; tot.z += h.z; tot.w += h.w;
            if ((u32)bb < myb) {
                bef.x += h.x; bef.y += h.y; bef.z += h.z; bef.w += h.w;
            }
        }
    }

    // --- Issue ALL 16 data loads (burst). The asm pin below (after the rank
    //     phase) forces all 64 components live -> allocator must budget
    //     ~110 VGPRs (cap 128 via launch_bounds) and cannot sink these.
    float4 r[ITEMS];
#pragma unroll
    for (int j = 0; j < ITEMS; ++j) {
        if (FULL || ((vmask >> j) & 1)) {
            r[j] = data[base + j * BLOCK + tid];
        } else {
            r[j] = make_float4(0.f, 0.f, 0.f, 0.f);
        }
    }

    // --- Phase A: ballots -> per-wave counts (LDS) + per-lane rank in regs.
    u64 ltm = (1ULL << lane) - 1ULL;
    u32 preP[ITEMS / 4] = {0, 0, 0, 0};
#pragma unroll
    for (int j = 0; j < ITEMS; ++j) {
        bool valid = FULL || ((vmask >> j) & 1);
        int l = (packed >> (2 * j)) & 3;
        u64 m0 = __ballot(valid && l == 0);
        u64 m1 = __ballot(valid && l == 1);
        u64 m2 = __ballot(valid && l == 2);
        u64 m3 = __ballot(valid && l == 3);
        if (lane == 0) {
            sh.s_pre[j][wave][0] = (u32)__popcll(m0);
            sh.s_pre[j][wave][1] = (u32)__popcll(m1);
            sh.s_pre[j][wave][2] = (u32)__popcll(m2);
            sh.s_pre[j][wave][3] = (u32)__popcll(m3);
        }
        u64 mm = (l == 0) ? m0 : (l == 1) ? m1 : (l == 2) ? m2 : m3;
        preP[j >> 2] |= ((u32)__popcll(mm & ltm)) << (8 * (j & 3));
    }

    // --- Wave-reduce bef/tot into LDS.
#pragma unroll
    for (int off = 32; off > 0; off >>= 1) {
        bef.x += (u32)__shfl_down((int)bef.x, off, 64);
        bef.y += (u32)__shfl_down((int)bef.y, off, 64);
        bef.z += (u32)__shfl_down((int)bef.z, off, 64);
        bef.w += (u32)__shfl_down((int)bef.w, off, 64);
        tot.x += (u32)__shfl_down((int)tot.x, off, 64);
        tot.y += (u32)__shfl_down((int)tot.y, off, 64);
        tot.z += (u32)__shfl_down((int)tot.z, off, 64);
        tot.w += (u32)__shfl_down((int)tot.w, off, 64);
    }
    if (lane == 0) {
        sh.s_red[wave][0] = bef.x; sh.s_red[wave][1] = bef.y;
        sh.s_red[wave][2] = bef.z; sh.s_red[wave][3] = bef.w;
        sh.s_red[wave][4] = tot.x; sh.s_red[wave][5] = tot.y;
        sh.s_red[wave][6] = tot.z; sh.s_red[wave][7] = tot.w;
    }
    __syncthreads();

    // --- Scan: wave w owns class w; 64 entries in (j, wave) order.
    {
        int c = wave;
        int e = lane;
        u32 x = sh.s_pre[e >> 2][e & 3][c];
        u32 orig = x;
#pragma unroll
        for (int off = 1; off < 64; off <<= 1) {
            u32 v = (u32)__shfl_up((int)x, off, 64);
            if (lane >= off) x += v;
        }
        sh.s_pre[e >> 2][e & 3][c] = x - orig;  // exclusive prefix in block
    }
    if (tid == 0) {
        u32 B0 = sh.s_red[0][0] + sh.s_red[1][0] + sh.s_red[2][0] + sh.s_red[3][0];
        u32 B1 = sh.s_red[0][1] + sh.s_red[1][1] + sh.s_red[2][1] + sh.s_red[3][1];
        u32 B2 = sh.s_red[0][2] + sh.s_red[1][2] + sh.s_red[2][2] + sh.s_red[3][2];
        u32 B3 = sh.s_red[0][3] + sh.s_red[1][3] + sh.s_red[2][3] + sh.s_red[3][3];
        u32 T0 = sh.s_red[0][4] + sh.s_red[1][4] + sh.s_red[2][4] + sh.s_red[3][4];
        u32 T1 = sh.s_red[0][5] + sh.s_red[1][5] + sh.s_red[2][5] + sh.s_red[3][5];
        u32 T2 = sh.s_red[0][6] + sh.s_red[1][6] + sh.s_red[2][6] + sh.s_red[3][6];
        u32 cb1 = T0, cb2 = T0 + T1, cb3 = T0 + T1 + T2;
        sh.s_bc[0] = B0;       sh.s_bc[1] = cb1 + B1;
        sh.s_bc[2] = cb2 + B2; sh.s_bc[3] = cb3 + B3;
        sh.s_bc[4] = cb1; sh.s_bc[5] = cb2; sh.s_bc[6] = cb3;
    }
    __syncthreads();

    u32 sb0 = sh.s_bc[0], sb1 = sh.s_bc[1], sb2 = sh.s_bc[2], sb3 = sh.s_bc[3];
    u32 cb1 = sh.s_bc[4], cb2 = sh.s_bc[5], cb3 = sh.s_bc[6];

    // --- Liveness pin: forces all 16 float4 to be in registers HERE.
#pragma unroll
    for (int j = 0; j < ITEMS; ++j) {
        asm volatile("" :: "v"(r[j].x), "v"(r[j].y), "v"(r[j].z), "v"(r[j].w));
    }

    // --- Process all 16: adjust + scatter + loss (plain cached stores).
    const float INV_M = 0.249999375f;  // 1/4.00001
    float loss = 0.f;
#pragma unroll
    for (int j = 0; j < ITEMS; ++j) {
        if (FULL || ((vmask >> j) & 1)) {
            int l = (packed >> (2 * j)) & 3;
            u32 pre = (preP[j >> 2] >> (8 * (j & 3))) & 255u;
            u32 bb = (l == 0) ? sb0 : (l == 1) ? sb1 : (l == 2) ? sb2 : sb3;
            u32 dst = bb + sh.s_pre[j][wave][l] + pre;
            float4 rr = r[j];
            float v = (l == 0) ? rr.x : (l == 1) ? rr.y
                                     : (l == 2) ? rr.z : rr.w;
            float adj = (v > 0.f) ? (v * INV_M - 0.5f) : (v * 4.00001f - 0.5f);
            if (l == 0) rr.x = adj;
            else if (l == 1) rr.y = adj;
            else if (l == 2) rr.z = adj;
            else rr.w = adj;
            out_data[dst] = rr;
            float mx = fmaxf(fmaxf(rr.x, rr.y), fmaxf(rr.z, rr.w));
            float se = __expf(rr.x - mx) + __expf(rr.y - mx) +
                       __expf(rr.z - mx) + __expf(rr.w - mx);
            loss += (mx + __logf(se)) - adj;  // -log p_true
        }
    }

    // --- Fused analytic label write for this block's range.
    {
        int t4base = base >> 2;
#pragma unroll
        for (int k = 0; k < 4; ++k) {
            int t4 = t4base + k * BLOCK + tid;
            int j0 = t4 * 4;
            if (FULL || j0 + 3 < N) {
                u32 j0u = (u32)j0;
                float4 rl;
                rl.x = (float)((j0u >= cb1) + (j0u >= cb2) + (j0u >= cb3));
                rl.y = (float)((j0u + 1 >= cb1) + (j0u + 1 >= cb2) + (j0u + 1 >= cb3));
                rl.z = (float)((j0u + 2 >= cb1) + (j0u + 2 >= cb2) + (j0u + 2 >= cb3));
                rl.w = (float)((j0u + 3 >= cb1) + (j0u + 3 >= cb2) + (j0u + 3 >= cb3));
                ((float4*)out_label)[t4] = rl;
            } else {
                for (int q = 0; q < 4; ++q) {
                    int jj = j0 + q;
                    if (jj >= 0 && jj < N) {
                        u32 ju = (u32)jj;
                        out_label[jj] =
                            (float)((ju >= cb1) + (ju >= cb2) + (ju >= cb3));
                    }
                }
            }
        }
    }

    // --- Block-reduce loss in double, one atomic per block; last block
    //     finalizes (proven in round 3; saves the 3rd dispatch).
    double d = (double)loss;
#pragma unroll
    for (int off = 32; off > 0; off >>= 1) d += __shfl_down(d, off, 64);
    if (lane == 0) sh.s_w[wave] = d;
    __syncthreads();
    if (tid == 0) {
        atomicAdd(acc, sh.s_w[0] + sh.s_w[1] + sh.s_w[2] + sh.s_w[3]);
        __threadfence();
        u32 old = atomicAdd(done, 1u);
        if (old == (u32)(gridDim.x - 1)) {
            double tl = atomicAdd(acc, 0.0);  // coherent read of final sum
            *out_loss = (float)(tl / (double)N);
        }
    }
}

__global__ void __launch_bounds__(BLOCK, 4)  // cap 128 VGPR (4 waves/EU)
sort_kernel(const float4* __restrict__ data, const u32* __restrict__ plab,
            int N, int nb, const u32* __restrict__ hist,
            float4* __restrict__ out_data, float* __restrict__ out_label,
            double* __restrict__ acc, u32* __restrict__ done,
            float* __restrict__ out_loss) {
    __shared__ SortShared sh;
    int base = blockIdx.x * CHUNK;
    if (base + CHUNK <= N) {
        sort_body<true>(sh, data, plab, N, nb, hist, out_data, out_label, acc,
                        done, out_loss);
    } else {
        sort_body<false>(sh, data, plab, N, nb, hist, out_data, out_label, acc,
                         done, out_loss);
    }
}

// ---------------------------------------------------------------------------
extern "C" void kernel_launch(void* const* d_in, const int* in_sizes, int n_in,
                              void* d_out, int out_size, void* d_ws,
                              size_t ws_size, hipStream_t stream) {
    const float* data = (const float*)d_in[0];
    const int* labels = (const int*)d_in[1];
    int N = in_sizes[1];
    int nb = (N + CHUNK - 1) / CHUNK;

    u32* hist = (u32*)d_ws;                     // nb*4 u32
    u32* plab = hist + (size_t)nb * 4;          // nb*BLOCK u32 (packed labels)
    double* acc =
        (double*)(((uintptr_t)(plab + (size_t)nb * BLOCK) + 15) &
                  ~(uintptr_t)15);
    u32* done = (u32*)(acc + 1);

    float* out = (float*)d_out;
    float* out_data = out;                   // N*4
    float* out_label = out + (size_t)N * 4;  // N
    float* out_loss = out + (size_t)N * 5;   // 1

    hist_kernel<<<nb, BLOCK, 0, stream>>>(labels, N, hist, plab, acc, done);
    sort_kernel<<<nb, BLOCK, 0, stream>>>((const float4*)data, plab, N, nb,
                                          hist, (float4*)out_data, out_label,
                                          acc, done, out_loss);
}